// Round 8
// baseline (212.664 us; speedup 1.0000x reference)
//
#include <hip/hip_runtime.h>
#include <math.h>

// Problem constants
#define NTOT   128      // batch n
#define NPOS   4096     // 64*64
#define PVCH   8        // position chunks for k_pv
#define PVLEN  512      // positions per k_pv block

// ---------------------------------------------------------------- fused q-MLP
// 32 blocks x 4 samples; 1024 threads. hprev(256) -> 512 -> 512 -> Q(288 @ c*288).
// Layers: thread (j, khalf) computes K/2 dot with 4-sample register tile;
// khalf 0 writes partial to tmp, khalf 1 combines + bias (+relu).
__global__ __launch_bounds__(1024) void k_mlpq(
    const float* __restrict__ hp,
    const float* __restrict__ q_w0, const float* __restrict__ q_b0,
    const float* __restrict__ q_w1, const float* __restrict__ q_b1,
    const float* __restrict__ q_w2, const float* __restrict__ q_b2,
    const int* __restrict__ cptr, float* __restrict__ Qb) {
  const int t = threadIdx.x;
  const int m0 = blockIdx.x * 4;
  __shared__ float xs[4][256];
  __shared__ float h1[4][512];
  __shared__ float h2[4][512];
  __shared__ float tmp[4][512];

  {
    int mi = t >> 8, k = t & 255;
    xs[mi][k] = hp[(size_t)(m0 + mi) * 256 + k];
  }
  __syncthreads();

  // ---- L0: K=256, N=512 ----
  {
    const int j = t & 511, kh = t >> 9;
    const float* wp = q_w0 + (size_t)(kh * 128) * 512 + j;
    float a0 = 0.f, a1 = 0.f, a2 = 0.f, a3 = 0.f;
#pragma unroll 8
    for (int k = 0; k < 128; ++k) {
      float wv = wp[(size_t)k * 512];
      int kk = kh * 128 + k;
      a0 += wv * xs[0][kk]; a1 += wv * xs[1][kk];
      a2 += wv * xs[2][kk]; a3 += wv * xs[3][kk];
    }
    if (kh == 0) { tmp[0][j] = a0; tmp[1][j] = a1; tmp[2][j] = a2; tmp[3][j] = a3; }
    __syncthreads();
    if (kh == 1) {
      float b = q_b0[j];
      h1[0][j] = fmaxf(tmp[0][j] + a0 + b, 0.f);
      h1[1][j] = fmaxf(tmp[1][j] + a1 + b, 0.f);
      h1[2][j] = fmaxf(tmp[2][j] + a2 + b, 0.f);
      h1[3][j] = fmaxf(tmp[3][j] + a3 + b, 0.f);
    }
    __syncthreads();
  }

  // ---- L1: K=512, N=512 ----
  {
    const int j = t & 511, kh = t >> 9;
    const float* wp = q_w1 + (size_t)(kh * 256) * 512 + j;
    float a0 = 0.f, a1 = 0.f, a2 = 0.f, a3 = 0.f;
#pragma unroll 8
    for (int k = 0; k < 256; ++k) {
      float wv = wp[(size_t)k * 512];
      int kk = kh * 256 + k;
      a0 += wv * h1[0][kk]; a1 += wv * h1[1][kk];
      a2 += wv * h1[2][kk]; a3 += wv * h1[3][kk];
    }
    if (kh == 0) { tmp[0][j] = a0; tmp[1][j] = a1; tmp[2][j] = a2; tmp[3][j] = a3; }
    __syncthreads();
    if (kh == 1) {
      float b = q_b1[j];
      h2[0][j] = fmaxf(tmp[0][j] + a0 + b, 0.f);
      h2[1][j] = fmaxf(tmp[1][j] + a1 + b, 0.f);
      h2[2][j] = fmaxf(tmp[2][j] + a2 + b, 0.f);
      h2[3][j] = fmaxf(tmp[3][j] + a3 + b, 0.f);
    }
    __syncthreads();
  }

  // ---- L2: K=512, N=288 at column offset c*288, ldw=1152, no relu ----
  {
    const int coff = cptr[0] * 288;
    const bool act = t < 576;
    const int j = (t < 288) ? t : t - 288;
    const int kh = (t < 288) ? 0 : 1;
    float a0 = 0.f, a1 = 0.f, a2 = 0.f, a3 = 0.f;
    if (act) {
      const float* wp = q_w2 + (size_t)(kh * 256) * 1152 + coff + j;
#pragma unroll 8
      for (int k = 0; k < 256; ++k) {
        float wv = wp[(size_t)k * 1152];
        int kk = kh * 256 + k;
        a0 += wv * h2[0][kk]; a1 += wv * h2[1][kk];
        a2 += wv * h2[2][kk]; a3 += wv * h2[3][kk];
      }
      if (kh == 0) { tmp[0][j] = a0; tmp[1][j] = a1; tmp[2][j] = a2; tmp[3][j] = a3; }
    }
    __syncthreads();
    if (act && kh == 1) {
      float b = q_b2[coff + j];
      Qb[(size_t)(m0 + 0) * 288 + j] = tmp[0][j] + a0 + b;
      Qb[(size_t)(m0 + 1) * 288 + j] = tmp[1][j] + a1 + b;
      Qb[(size_t)(m0 + 2) * 288 + j] = tmp[2][j] + a2 + b;
      Qb[(size_t)(m0 + 3) * 288 + j] = tmp[3][j] + a3 + b;
    }
  }
}

// ---------------------------------------------------------------- logits + full softmax + S-part
// One block per sample n (1024 threads, 4 positions each). Produces:
//  - Pw[n][pos][4]: normalized attention weights
//  - ans S-dims (q*184+120+uv), Q-dims (736..1023), scalars (1024,1025)
__global__ __launch_bounds__(1024) void k_logits(
    const float* __restrict__ x, const float* __restrict__ Qb,
    const float* __restrict__ r_prev, const float* __restrict__ a_prev,
    float* __restrict__ Pw, float* __restrict__ ans) {
  const int n = blockIdx.x;
  const int t = threadIdx.x;
  const int wave = t >> 6, lane = t & 63;

  __shared__ float Qs[4][72];
  __shared__ float ct[64][8];          // cos((i+1)(u+1)pi/64): ca == cb (h=w=64)
  __shared__ float cbQ[4 * 576];       // [q][j][u] padded to 9
  __shared__ float4 wlds[NPOS];        // 64 KB: logits -> exp weights
  __shared__ float red[4][16];
  __shared__ float mfin[4], lfin[4];
  __shared__ float rowSum[64][4][8];   // per i-row: sum_j w[j][q]*cb[j][v]

  const float PI64 = 3.14159265358979323846f / 64.f;

  if (t < 288) Qs[t / 72][t % 72] = Qb[(size_t)n * 288 + t];
  if (t < 512) {
    int i = t >> 3, u = t & 7;
    ct[i][u] = cosf((float)((i + 1) * (u + 1)) * PI64);
  }
  __syncthreads();

  // cbQ[q][j][u] = sum_v ct[j][v] * Q[q][8+u*8+v]
  for (int e = t; e < 2048; e += 1024) {
    int q = e >> 9, j = (e >> 3) & 63, u = e & 7;
    float s = 0.f;
#pragma unroll
    for (int v = 0; v < 8; ++v) s += ct[j][v] * Qs[q][8 + u * 8 + v];
    cbQ[q * 576 + j * 9 + u] = s;
  }
  __syncthreads();

  // logits: thread handles pos = r*1024 + t  (j = lane, i = r*16 + wave)
  const float* xp = x + (size_t)n * NPOS * 128;
  float lmax[4] = {-1e30f, -1e30f, -1e30f, -1e30f};
#pragma unroll
  for (int r = 0; r < 4; ++r) {
    const int pos = r * 1024 + t;
    const int i = r * 16 + wave;
    const float4* xr = reinterpret_cast<const float4*>(xp + (size_t)pos * 128);
    float4 xa = xr[0], xb = xr[1];
    float lg[4];
#pragma unroll
    for (int q = 0; q < 4; ++q) {
      float s = xa.x * Qs[q][0] + xa.y * Qs[q][1] + xa.z * Qs[q][2] + xa.w * Qs[q][3]
              + xb.x * Qs[q][4] + xb.y * Qs[q][5] + xb.z * Qs[q][6] + xb.w * Qs[q][7];
      const float* cq = cbQ + q * 576 + lane * 9;
      float s2 = 0.f;
#pragma unroll
      for (int u = 0; u < 8; ++u) s2 += ct[i][u] * cq[u];
      lg[q] = s + s2;
      lmax[q] = fmaxf(lmax[q], lg[q]);
    }
    wlds[pos] = make_float4(lg[0], lg[1], lg[2], lg[3]);
  }

  // block max
#pragma unroll
  for (int off = 32; off; off >>= 1)
#pragma unroll
    for (int q = 0; q < 4; ++q) lmax[q] = fmaxf(lmax[q], __shfl_xor(lmax[q], off));
  if (lane == 0)
#pragma unroll
    for (int q = 0; q < 4; ++q) red[q][wave] = lmax[q];
  __syncthreads();
  if (t < 4) {
    float m = red[t][0];
#pragma unroll
    for (int w = 1; w < 16; ++w) m = fmaxf(m, red[t][w]);
    mfin[t] = m;
  }
  __syncthreads();

  // exp + block sum
  float lsum[4] = {0.f, 0.f, 0.f, 0.f};
#pragma unroll
  for (int r = 0; r < 4; ++r) {
    const int pos = r * 1024 + t;
    float4 w = wlds[pos];
    w.x = __expf(w.x - mfin[0]);
    w.y = __expf(w.y - mfin[1]);
    w.z = __expf(w.z - mfin[2]);
    w.w = __expf(w.w - mfin[3]);
    wlds[pos] = w;
    lsum[0] += w.x; lsum[1] += w.y; lsum[2] += w.z; lsum[3] += w.w;
  }
#pragma unroll
  for (int off = 32; off; off >>= 1)
#pragma unroll
    for (int q = 0; q < 4; ++q) lsum[q] += __shfl_xor(lsum[q], off);
  if (lane == 0)
#pragma unroll
    for (int q = 0; q < 4; ++q) red[q][wave] = lsum[q];
  __syncthreads();
  if (t < 4) {
    float s = 0.f;
#pragma unroll
    for (int w = 0; w < 16; ++w) s += red[t][w];
    lfin[t] = s;
  }
  __syncthreads();

  const float i0 = 1.f / lfin[0], i1 = 1.f / lfin[1];
  const float i2 = 1.f / lfin[2], i3 = 1.f / lfin[3];

  // normalized weights out (coalesced float4)
  float4* Pw4 = reinterpret_cast<float4*>(Pw) + (size_t)n * NPOS;
#pragma unroll
  for (int r = 0; r < 4; ++r) {
    const int pos = r * 1024 + t;
    float4 w = wlds[pos];
    Pw4[pos] = make_float4(w.x * i0, w.y * i1, w.z * i2, w.w * i3);
  }

  // rowSum[i][q][v] = inv[q] * sum_j w[i*64+j][q] * ct[j][v]
  for (int o = t; o < 2048; o += 1024) {
    int i = o >> 5, q = (o >> 3) & 3, v = o & 7;
    float s0 = 0.f, s1 = 0.f, s2 = 0.f, s3 = 0.f;
    const float* wb = reinterpret_cast<const float*>(&wlds[i * 64]) + q;
#pragma unroll 8
    for (int j = 0; j < 64; j += 4) {
      s0 += wb[(j + 0) * 4] * ct[j + 0][v];
      s1 += wb[(j + 1) * 4] * ct[j + 1][v];
      s2 += wb[(j + 2) * 4] * ct[j + 2][v];
      s3 += wb[(j + 3) * 4] * ct[j + 3][v];
    }
    float inv = (q == 0) ? i0 : (q == 1) ? i1 : (q == 2) ? i2 : i3;
    rowSum[i][q][v] = ((s0 + s1) + (s2 + s3)) * inv;
  }
  __syncthreads();

  // a_S[q][uv] = sum_i ct[i][u] * rowSum[i][q][v]; plus Q-part + scalars
  float* ap = ans + (size_t)n * 1026;
  if (t < 256) {
    int q = t >> 6, uv = t & 63, u = uv >> 3, v = uv & 7;
    float s = 0.f;
#pragma unroll 8
    for (int i = 0; i < 64; ++i) s += ct[i][u] * rowSum[i][q][v];
    ap[q * 184 + 120 + uv] = s;
  } else if (t < 544) {
    int qi = t - 256;
    ap[736 + qi] = Qs[qi / 72][qi % 72];
  } else if (t == 544) {
    ap[1024] = r_prev[n];
  } else if (t == 545) {
    ap[1025] = a_prev[n];
  }
}

// ---------------------------------------------------------------- weighted V (x-channels only)
// grid (PVCH, NTOT); block: 512 positions; wave: 128 positions;
// lane<60 owns x channels 8+2l, 8+2l+1; 16 loads in flight per lane.
__global__ __launch_bounds__(256, 4) void k_pv(
    const float* __restrict__ x, const float* __restrict__ Pw,
    float* __restrict__ pvp) {
  const int n = blockIdx.y, ck = blockIdx.x;
  const int t = threadIdx.x, wave = t >> 6, lane = t & 63;
  __shared__ float4 wl[PVLEN];
  __shared__ __align__(16) float part[4][4][120];

  const int base = ck * PVLEN;
  {
    const float4* src = reinterpret_cast<const float4*>(Pw) + (size_t)n * NPOS + base;
    wl[t] = src[t];
    wl[t + 256] = src[t + 256];
  }
  __syncthreads();

  const int xl = (lane < 60) ? lane : 59;
  const float* vb = x + ((size_t)n * NPOS + base + wave * 128) * 128 + 8 + 2 * xl;

  float ax0[4] = {0.f, 0.f, 0.f, 0.f};
  float ax1[4] = {0.f, 0.f, 0.f, 0.f};
#pragma unroll
  for (int b = 0; b < 8; ++b) {
    float2 v0  = *reinterpret_cast<const float2*>(vb + (size_t)(b * 16 + 0)  * 128);
    float2 v1  = *reinterpret_cast<const float2*>(vb + (size_t)(b * 16 + 1)  * 128);
    float2 v2  = *reinterpret_cast<const float2*>(vb + (size_t)(b * 16 + 2)  * 128);
    float2 v3  = *reinterpret_cast<const float2*>(vb + (size_t)(b * 16 + 3)  * 128);
    float2 v4  = *reinterpret_cast<const float2*>(vb + (size_t)(b * 16 + 4)  * 128);
    float2 v5  = *reinterpret_cast<const float2*>(vb + (size_t)(b * 16 + 5)  * 128);
    float2 v6  = *reinterpret_cast<const float2*>(vb + (size_t)(b * 16 + 6)  * 128);
    float2 v7  = *reinterpret_cast<const float2*>(vb + (size_t)(b * 16 + 7)  * 128);
    float2 v8  = *reinterpret_cast<const float2*>(vb + (size_t)(b * 16 + 8)  * 128);
    float2 v9  = *reinterpret_cast<const float2*>(vb + (size_t)(b * 16 + 9)  * 128);
    float2 v10 = *reinterpret_cast<const float2*>(vb + (size_t)(b * 16 + 10) * 128);
    float2 v11 = *reinterpret_cast<const float2*>(vb + (size_t)(b * 16 + 11) * 128);
    float2 v12 = *reinterpret_cast<const float2*>(vb + (size_t)(b * 16 + 12) * 128);
    float2 v13 = *reinterpret_cast<const float2*>(vb + (size_t)(b * 16 + 13) * 128);
    float2 v14 = *reinterpret_cast<const float2*>(vb + (size_t)(b * 16 + 14) * 128);
    float2 v15 = *reinterpret_cast<const float2*>(vb + (size_t)(b * 16 + 15) * 128);
#define ACC(VV, II)                                                              \
    {                                                                            \
      float4 w = wl[wave * 128 + b * 16 + II];                                   \
      ax0[0] += w.x * VV.x; ax1[0] += w.x * VV.y;                                \
      ax0[1] += w.y * VV.x; ax1[1] += w.y * VV.y;                                \
      ax0[2] += w.z * VV.x; ax1[2] += w.z * VV.y;                                \
      ax0[3] += w.w * VV.x; ax1[3] += w.w * VV.y;                                \
    }
    ACC(v0, 0)  ACC(v1, 1)  ACC(v2, 2)  ACC(v3, 3)
    ACC(v4, 4)  ACC(v5, 5)  ACC(v6, 6)  ACC(v7, 7)
    ACC(v8, 8)  ACC(v9, 9)  ACC(v10, 10) ACC(v11, 11)
    ACC(v12, 12) ACC(v13, 13) ACC(v14, 14) ACC(v15, 15)
#undef ACC
  }
  if (lane < 60) {
#pragma unroll
    for (int q = 0; q < 4; ++q)
      *reinterpret_cast<float2*>(&part[wave][q][2 * lane]) = make_float2(ax0[q], ax1[q]);
  }
  __syncthreads();

  float* op = pvp + ((size_t)ck * NTOT + n) * 480;
  for (int idx = t; idx < 480; idx += 256) {
    const int q = idx / 120, d = idx - q * 120;
    op[idx] = (part[0][q][d] + part[1][q][d]) + (part[2][q][d] + part[3][q][d]);
  }
}

// ---------------------------------------------------------------- fused a-MLP
// 32 blocks x 4 samples; 1024 threads. A(1026) -> 512 -> 512 -> 256 (am).
// Staging gathers x-dims from the 8 pvp chunk partials; rest from ans.
__global__ __launch_bounds__(1024) void k_mlpa(
    const float* __restrict__ ans, const float* __restrict__ pvp,
    const float* __restrict__ a_w0, const float* __restrict__ a_b0,
    const float* __restrict__ a_w1, const float* __restrict__ a_b1,
    const float* __restrict__ a_w2, const float* __restrict__ a_b2,
    float* __restrict__ am) {
  const int t = threadIdx.x;
  const int m0 = blockIdx.x * 4;
  __shared__ float xs[4][1032];
  __shared__ float h1[4][512];
  __shared__ float h2[4][512];
  __shared__ float tmp[4][512];

  // stage A rows (x-dims reduced from pvp)
  for (int idx = t; idx < 4 * 1026; idx += 1024) {
    int mi = idx / 1026, col = idx - mi * 1026;
    float s;
    int q = col / 184, d = col - q * 184;
    if (col < 736 && d < 120) {
      const size_t eo = (size_t)(m0 + mi) * 480 + q * 120 + d;
      float s0 = pvp[(size_t)(0 * NTOT) * 480 + eo];
      float s1 = pvp[(size_t)(1 * NTOT) * 480 + eo];
      float s2 = pvp[(size_t)(2 * NTOT) * 480 + eo];
      float s3 = pvp[(size_t)(3 * NTOT) * 480 + eo];
      s0 += pvp[(size_t)(4 * NTOT) * 480 + eo];
      s1 += pvp[(size_t)(5 * NTOT) * 480 + eo];
      s2 += pvp[(size_t)(6 * NTOT) * 480 + eo];
      s3 += pvp[(size_t)(7 * NTOT) * 480 + eo];
      s = (s0 + s1) + (s2 + s3);
    } else {
      s = ans[(size_t)(m0 + mi) * 1026 + col];
    }
    xs[mi][col] = s;
  }
  __syncthreads();

  // ---- L0: K=1026 (2 halves of 513), N=512 ----
  {
    const int j = t & 511, kh = t >> 9;
    const float* wp = a_w0 + (size_t)(kh * 513) * 512 + j;
    float a0 = 0.f, a1 = 0.f, a2 = 0.f, a3 = 0.f;
#pragma unroll 8
    for (int k = 0; k < 513; ++k) {
      float wv = wp[(size_t)k * 512];
      int kk = kh * 513 + k;
      a0 += wv * xs[0][kk]; a1 += wv * xs[1][kk];
      a2 += wv * xs[2][kk]; a3 += wv * xs[3][kk];
    }
    if (kh == 0) { tmp[0][j] = a0; tmp[1][j] = a1; tmp[2][j] = a2; tmp[3][j] = a3; }
    __syncthreads();
    if (kh == 1) {
      float b = a_b0[j];
      h1[0][j] = fmaxf(tmp[0][j] + a0 + b, 0.f);
      h1[1][j] = fmaxf(tmp[1][j] + a1 + b, 0.f);
      h1[2][j] = fmaxf(tmp[2][j] + a2 + b, 0.f);
      h1[3][j] = fmaxf(tmp[3][j] + a3 + b, 0.f);
    }
    __syncthreads();
  }

  // ---- L1: K=512, N=512 ----
  {
    const int j = t & 511, kh = t >> 9;
    const float* wp = a_w1 + (size_t)(kh * 256) * 512 + j;
    float a0 = 0.f, a1 = 0.f, a2 = 0.f, a3 = 0.f;
#pragma unroll 8
    for (int k = 0; k < 256; ++k) {
      float wv = wp[(size_t)k * 512];
      int kk = kh * 256 + k;
      a0 += wv * h1[0][kk]; a1 += wv * h1[1][kk];
      a2 += wv * h1[2][kk]; a3 += wv * h1[3][kk];
    }
    if (kh == 0) { tmp[0][j] = a0; tmp[1][j] = a1; tmp[2][j] = a2; tmp[3][j] = a3; }
    __syncthreads();
    if (kh == 1) {
      float b = a_b1[j];
      h2[0][j] = fmaxf(tmp[0][j] + a0 + b, 0.f);
      h2[1][j] = fmaxf(tmp[1][j] + a1 + b, 0.f);
      h2[2][j] = fmaxf(tmp[2][j] + a2 + b, 0.f);
      h2[3][j] = fmaxf(tmp[3][j] + a3 + b, 0.f);
    }
    __syncthreads();
  }

  // ---- L2: K=512 (4 quarters of 128), N=256, identity ----
  {
    const int j = t & 255, kq = t >> 8;
    const float* wp = a_w2 + (size_t)(kq * 128) * 256 + j;
    float a0 = 0.f, a1 = 0.f, a2 = 0.f, a3 = 0.f;
#pragma unroll 8
    for (int k = 0; k < 128; ++k) {
      float wv = wp[(size_t)k * 256];
      int kk = kq * 128 + k;
      a0 += wv * h2[0][kk]; a1 += wv * h2[1][kk];
      a2 += wv * h2[2][kk]; a3 += wv * h2[3][kk];
    }
    if (kq == 0) { tmp[0][j] = a0; tmp[1][j] = a1; tmp[2][j] = a2; tmp[3][j] = a3; }
    if (kq == 1) { tmp[0][256 + j] = a0; tmp[1][256 + j] = a1; tmp[2][256 + j] = a2; tmp[3][256 + j] = a3; }
    if (kq == 2) { h1[0][j] = a0; h1[1][j] = a1; h1[2][j] = a2; h1[3][j] = a3; }
    __syncthreads();
    if (kq == 3) {
      float b = a_b2[j];
      am[(size_t)(m0 + 0) * 256 + j] = tmp[0][j] + tmp[0][256 + j] + h1[0][j] + a0 + b;
      am[(size_t)(m0 + 1) * 256 + j] = tmp[1][j] + tmp[1][256 + j] + h1[1][j] + a1 + b;
      am[(size_t)(m0 + 2) * 256 + j] = tmp[2][j] + tmp[2][256 + j] + h1[2][j] + a2 + b;
      am[(size_t)(m0 + 3) * 256 + j] = tmp[3][j] + tmp[3][256 + j] + h1[3][j] + a3 + b;
    }
  }
}

// ---------------------------------------------------------------- LSTM gates
__global__ __launch_bounds__(256) void k_gates(
    const float* __restrict__ am, const float* __restrict__ hp,
    const float* __restrict__ w_ih, const float* __restrict__ w_hh,
    const float* __restrict__ b_ih, const float* __restrict__ b_hh,
    float* __restrict__ gbuf) {
  const int t = threadIdx.x;
  const int n0 = blockIdx.x * 2;
  const int r0 = blockIdx.y * 64;
  __shared__ float xs[2][256], hs[2][256];
  __shared__ float red[64][4][5];
#pragma unroll
  for (int s = 0; s < 2; ++s) {
    xs[s][t] = am[(size_t)(n0 + s) * 256 + t];
    hs[s][t] = hp[(size_t)(n0 + s) * 256 + t];
  }
  __syncthreads();
  const int r = t >> 2, kq = t & 3;
  const int row = r0 + r;
  const float4* wi = reinterpret_cast<const float4*>(w_ih + (size_t)row * 256 + kq * 64);
  const float4* wh = reinterpret_cast<const float4*>(w_hh + (size_t)row * 256 + kq * 64);
  float s00 = 0.f, s01 = 0.f, s10 = 0.f, s11 = 0.f;
#pragma unroll
  for (int i = 0; i < 16; ++i) {
    float4 a = wi[i], b = wh[i];
    const int k4 = kq * 64 + i * 4;
    s00 += a.x * xs[0][k4] + a.y * xs[0][k4 + 1] + a.z * xs[0][k4 + 2] + a.w * xs[0][k4 + 3];
    s01 += a.x * xs[1][k4] + a.y * xs[1][k4 + 1] + a.z * xs[1][k4 + 2] + a.w * xs[1][k4 + 3];
    s10 += b.x * hs[0][k4] + b.y * hs[0][k4 + 1] + b.z * hs[0][k4 + 2] + b.w * hs[0][k4 + 3];
    s11 += b.x * hs[1][k4] + b.y * hs[1][k4 + 1] + b.z * hs[1][k4 + 2] + b.w * hs[1][k4 + 3];
  }
  red[r][kq][0] = s00; red[r][kq][1] = s01; red[r][kq][2] = s10; red[r][kq][3] = s11;
  __syncthreads();
  if (t < 128) {
    const int rr = t >> 1, s = t & 1;
    float g = b_ih[r0 + rr] + b_hh[r0 + rr];
#pragma unroll
    for (int k = 0; k < 4; ++k) g += red[rr][k][s] + red[rr][k][2 + s];
    gbuf[(size_t)(n0 + s) * 1024 + r0 + rr] = g;
  }
}

// ---------------------------------------------------------------- LSTM elementwise + heads
__global__ __launch_bounds__(256) void k_lstm2(
    const float* __restrict__ gbuf, const float* __restrict__ cp,
    const float* __restrict__ p_w, const float* __restrict__ p_b,
    const float* __restrict__ v_w, const float* __restrict__ v_b,
    float* __restrict__ out) {
  const int t = threadIdx.x;
  const int n0 = blockIdx.x * 2;
  __shared__ float h2[2][256];
#pragma unroll
  for (int s = 0; s < 2; ++s) {
    const size_t gb = (size_t)(n0 + s) * 1024;
    float gi = gbuf[gb + t], gf = gbuf[gb + 256 + t];
    float gg = gbuf[gb + 512 + t], go = gbuf[gb + 768 + t];
    float si = 1.f / (1.f + __expf(-gi));
    float sf = 1.f / (1.f + __expf(-gf));
    float so = 1.f / (1.f + __expf(-go));
    float c2 = sf * cp[(size_t)(n0 + s) * 256 + t] + si * tanhf(gg);
    h2[s][t] = so * tanhf(c2);
  }
  __syncthreads();
  if (t < 72) {
    const int si = t / 36, r = t % 36, iv = r / 18, j = r % 18;
    const float* W = iv ? v_w : p_w;
    const float* B = iv ? v_b : p_b;
    float s = B[j];
#pragma unroll 8
    for (int k = 0; k < 256; ++k) s += h2[si][k] * W[k * 18 + j];
    out[(size_t)iv * (NTOT * 18) + (size_t)(n0 + si) * 18 + j] = s;
  }
}

// ---------------------------------------------------------------- launch
extern "C" void kernel_launch(void* const* d_in, const int* in_sizes, int n_in,
                              void* d_out, int out_size, void* d_ws, size_t ws_size,
                              hipStream_t stream) {
  const float* x      = (const float*)d_in[0];
  const int*   cptr   = (const int*)d_in[1];
  const float* r_prev = (const float*)d_in[2];
  const float* a_prev = (const float*)d_in[3];
  const float* hprev  = (const float*)d_in[4];
  const float* cprev  = (const float*)d_in[5];
  const float* q_w0 = (const float*)d_in[6];
  const float* q_b0 = (const float*)d_in[7];
  const float* q_w1 = (const float*)d_in[8];
  const float* q_b1 = (const float*)d_in[9];
  const float* q_w2 = (const float*)d_in[10];
  const float* q_b2 = (const float*)d_in[11];
  const float* a_w0 = (const float*)d_in[12];
  const float* a_b0 = (const float*)d_in[13];
  const float* a_w1 = (const float*)d_in[14];
  const float* a_b1 = (const float*)d_in[15];
  const float* a_w2 = (const float*)d_in[16];
  const float* a_b2 = (const float*)d_in[17];
  const float* w_ih = (const float*)d_in[18];
  const float* w_hh = (const float*)d_in[19];
  const float* b_ih = (const float*)d_in[20];
  const float* b_hh = (const float*)d_in[21];
  const float* p_w  = (const float*)d_in[22];
  const float* p_b  = (const float*)d_in[23];
  const float* v_w  = (const float*)d_in[24];
  const float* v_b  = (const float*)d_in[25];
  float* out = (float*)d_out;
  float* ws  = (float*)d_ws;

  // workspace layout (floats)
  float* Qb  = ws;                // 36864   (128 x 288) final Q
  float* Pw  = Qb  + 36864;       // 2097152 (128 x 4096 x 4) normalized weights
  float* pvp = Pw  + 2097152;     // 491520  (8 x 128 x 480) pv partials
  float* ans = pvp + 491520;      // 131328  (128 x 1026)
  float* am  = ans + 131328;      // 32768   (128 x 256)
  float* gbuf= am  + 32768;       // 131072  (128 x 1024)

  // fused q-MLP -> Qb
  k_mlpq<<<32, 1024, 0, stream>>>(hprev, q_w0, q_b0, q_w1, q_b1, q_w2, q_b2, cptr, Qb);

  // attention: full softmax + S/Q-part of ans, then x-channel PV partials
  k_logits<<<NTOT, 1024, 0, stream>>>(x, Qb, r_prev, a_prev, Pw, ans);
  k_pv<<<dim3(PVCH, NTOT), 256, 0, stream>>>(x, Pw, pvp);

  // fused a-MLP -> am (stages pvp gather + ans)
  k_mlpa<<<32, 1024, 0, stream>>>(ans, pvp, a_w0, a_b0, a_w1, a_b1, a_w2, a_b2, am);

  // LSTM + heads
  k_gates<<<dim3(64, 16), 256, 0, stream>>>(am, hprev, w_ih, w_hh, b_ih, b_hh, gbuf);
  k_lstm2<<<64, 256, 0, stream>>>(gbuf, cprev, p_w, p_b, v_w, v_b, out);
}

// Round 9
// 143.411 us; speedup vs baseline: 1.4829x; 1.4829x over previous
//
#include <hip/hip_runtime.h>
#include <math.h>

// Problem constants
#define NTOT   128      // batch n
#define NPOS   4096     // 64*64
#define PVCH   8        // position chunks for k_pv
#define PVLEN  512      // positions per k_pv block
#define LCH    4        // logits chunks per sample
#define LCLEN  1024     // positions per logits chunk

// ---------------------------------------------------------------- split-K GEMM with fused A-reduce
// A_eff[m][k] = Ad ? Ad[m][k] : act(sum_z pA[z][m][k] + biasA[k])
// If pvR != nullptr (a_w0 layer): cols k<736 with (k%184)<120 are gather-reduced
// from the 8 k_pv chunk partials with per-logits-chunk softmax scales scl[m][lch][q].
__global__ __launch_bounds__(256) void k_gemm(
    const float* __restrict__ Ad, const float* __restrict__ pA,
    const float* __restrict__ biasA, int nzA, int reluA,
    const float* __restrict__ pvR, const float* __restrict__ scl,
    const float* __restrict__ W, float* __restrict__ pbuf,
    int N, int K, int ldw, int gkc, const int* __restrict__ cptr, int cmul) {
  __shared__ float Xs[4][128];
  const int t  = threadIdx.x;
  const int j  = blockIdx.x * 256 + t;
  const int m0 = blockIdx.y * 4;
  const int k0 = blockIdx.z * gkc;
  const int klen = min(gkc, K - k0);
  const int coff = cptr[0] * cmul;

  for (int idx = t; idx < 4 * klen; idx += 256) {
    int mi = idx / klen;
    int kk = idx - mi * klen;
    int col = k0 + kk;
    float s;
    if (Ad) {
      bool pv = false;
      int q = 0, d = 0;
      if (pvR && col < 736) {
        q = col / 184; d = col - q * 184;
        pv = (d < 120);
      }
      if (pv) {
        const size_t eo = (size_t)(m0 + mi) * 480 + q * 120 + d;
        const float* scp = scl + (size_t)(m0 + mi) * 16 + q;
        float p0 = pvR[(size_t)(0 * NTOT) * 480 + eo];
        float p1 = pvR[(size_t)(1 * NTOT) * 480 + eo];
        float p2 = pvR[(size_t)(2 * NTOT) * 480 + eo];
        float p3 = pvR[(size_t)(3 * NTOT) * 480 + eo];
        float p4 = pvR[(size_t)(4 * NTOT) * 480 + eo];
        float p5 = pvR[(size_t)(5 * NTOT) * 480 + eo];
        float p6 = pvR[(size_t)(6 * NTOT) * 480 + eo];
        float p7 = pvR[(size_t)(7 * NTOT) * 480 + eo];
        s = scp[0] * (p0 + p1) + scp[4] * (p2 + p3)
          + scp[8] * (p4 + p5) + scp[12] * (p6 + p7);
      } else {
        s = Ad[(size_t)(m0 + mi) * K + col];
      }
    } else {
      float s0 = biasA[col], s1 = 0.f, s2 = 0.f, s3 = 0.f;
      int z = 0;
      for (; z + 4 <= nzA; z += 4) {
        s0 += pA[((size_t)(z + 0) * NTOT + m0 + mi) * K + col];
        s1 += pA[((size_t)(z + 1) * NTOT + m0 + mi) * K + col];
        s2 += pA[((size_t)(z + 2) * NTOT + m0 + mi) * K + col];
        s3 += pA[((size_t)(z + 3) * NTOT + m0 + mi) * K + col];
      }
      for (; z < nzA; ++z) s0 += pA[((size_t)z * NTOT + m0 + mi) * K + col];
      s = (s0 + s1) + (s2 + s3);
      if (reluA) s = fmaxf(s, 0.f);
    }
    Xs[mi][kk] = s;
  }
  __syncthreads();

  if (j < N) {
    float acc[4];
#pragma unroll
    for (int mi = 0; mi < 4; ++mi) acc[mi] = 0.f;
    const float* wp = W + (size_t)k0 * ldw + coff + j;
#pragma unroll 16
    for (int kk = 0; kk < klen; ++kk) {
      float wv = wp[(size_t)kk * ldw];
#pragma unroll
      for (int mi = 0; mi < 4; ++mi) acc[mi] = fmaf(Xs[mi][kk], wv, acc[mi]);
    }
    float* op = pbuf + ((size_t)blockIdx.z * NTOT + m0) * N + j;
#pragma unroll
    for (int mi = 0; mi < 4; ++mi) op[(size_t)mi * N] = acc[mi];
  }
}

// ---------------------------------------------------------------- logits, chunk-local softmax
// grid (LCH, NTOT), 256 threads, 1024 positions per block (i-rows [ck*16, ck*16+16)).
// Writes UNNORMALIZED w = exp(lg - m_chunk) to Pw, chunk stats (m,l), raw
// rowSumP[i][q][v] = sum_j w * ct[j][v]; block ck==0 writes ans Q-part + scalars.
__global__ __launch_bounds__(256) void k_logit_part(
    const float* __restrict__ x, const float* __restrict__ pQ,
    const float* __restrict__ q_b2, const int* __restrict__ cptr,
    const float* __restrict__ r_prev, const float* __restrict__ a_prev,
    float* __restrict__ Pw, float* __restrict__ stats,
    float* __restrict__ rowSumP, float* __restrict__ ans) {
  const int ck = blockIdx.x;
  const int n  = blockIdx.y;
  const int t  = threadIdx.x;
  const int wave = t >> 6, lane = t & 63;

  __shared__ float Qs[4][72];
  __shared__ float ct[64][8];          // cos((i+1)(u+1)pi/64), h==w
  __shared__ float cbQ[4 * 576];       // [q][j][u] padded to 9
  __shared__ float4 wlds[LCLEN];       // 16 KB: logits -> exp weights
  __shared__ float red[4][4];
  __shared__ float mfin[4], lfin[4];

  const float PI64 = 3.14159265358979323846f / 64.f;

  // Q reduce from split-K partials (z=8)
  {
    const int coff = cptr[0] * 288;
    for (int idx = t; idx < 288; idx += 256) {
      float s = q_b2[coff + idx];
#pragma unroll
      for (int z = 0; z < 8; ++z) s += pQ[((size_t)z * NTOT + n) * 288 + idx];
      Qs[idx / 72][idx % 72] = s;
    }
  }
  for (int e = t; e < 512; e += 256) {
    int i = e >> 3, u = e & 7;
    ct[i][u] = cosf((float)((i + 1) * (u + 1)) * PI64);
  }
  __syncthreads();

  // cbQ[q][j][u] = sum_v ct[j][v] * Q[q][8+u*8+v]
  for (int e = t; e < 2048; e += 256) {
    int q = e >> 9, j = (e >> 3) & 63, u = e & 7;
    float s = 0.f;
#pragma unroll
    for (int v = 0; v < 8; ++v) s += ct[j][v] * Qs[q][8 + u * 8 + v];
    cbQ[q * 576 + j * 9 + u] = s;
  }
  __syncthreads();

  const int base = ck * LCLEN;
  const float* xp = x + (size_t)n * NPOS * 128;

  float lmax[4] = {-1e30f, -1e30f, -1e30f, -1e30f};
#pragma unroll
  for (int r = 0; r < 4; ++r) {
    const int local = r * 256 + t;
    const int pos = base + local;
    const int i = ck * 16 + r * 4 + wave;
    const float4* xr = reinterpret_cast<const float4*>(xp + (size_t)pos * 128);
    float4 xa = xr[0], xb = xr[1];
    float lg[4];
#pragma unroll
    for (int q = 0; q < 4; ++q) {
      float s = xa.x * Qs[q][0] + xa.y * Qs[q][1] + xa.z * Qs[q][2] + xa.w * Qs[q][3]
              + xb.x * Qs[q][4] + xb.y * Qs[q][5] + xb.z * Qs[q][6] + xb.w * Qs[q][7];
      const float* cq = cbQ + q * 576 + lane * 9;
      float s2 = 0.f;
#pragma unroll
      for (int u = 0; u < 8; ++u) s2 += ct[i][u] * cq[u];
      lg[q] = s + s2;
      lmax[q] = fmaxf(lmax[q], lg[q]);
    }
    wlds[local] = make_float4(lg[0], lg[1], lg[2], lg[3]);
  }

  // chunk max
#pragma unroll
  for (int off = 32; off; off >>= 1)
#pragma unroll
    for (int q = 0; q < 4; ++q) lmax[q] = fmaxf(lmax[q], __shfl_xor(lmax[q], off));
  if (lane == 0)
#pragma unroll
    for (int q = 0; q < 4; ++q) red[q][wave] = lmax[q];
  __syncthreads();
  if (t < 4) mfin[t] = fmaxf(fmaxf(red[t][0], red[t][1]), fmaxf(red[t][2], red[t][3]));
  __syncthreads();

  // exp (unnormalized) -> wlds + Pw, chunk sum
  float4* Pw4 = reinterpret_cast<float4*>(Pw) + (size_t)n * NPOS + base;
  float lsum[4] = {0.f, 0.f, 0.f, 0.f};
#pragma unroll
  for (int r = 0; r < 4; ++r) {
    const int local = r * 256 + t;
    float4 w = wlds[local];
    w.x = __expf(w.x - mfin[0]);
    w.y = __expf(w.y - mfin[1]);
    w.z = __expf(w.z - mfin[2]);
    w.w = __expf(w.w - mfin[3]);
    wlds[local] = w;
    Pw4[local] = w;
    lsum[0] += w.x; lsum[1] += w.y; lsum[2] += w.z; lsum[3] += w.w;
  }
#pragma unroll
  for (int off = 32; off; off >>= 1)
#pragma unroll
    for (int q = 0; q < 4; ++q) lsum[q] += __shfl_xor(lsum[q], off);
  if (lane == 0)
#pragma unroll
    for (int q = 0; q < 4; ++q) red[q][wave] = lsum[q];
  __syncthreads();
  if (t < 4) {
    lfin[t] = red[t][0] + red[t][1] + red[t][2] + red[t][3];
    stats[((size_t)n * LCH + ck) * 8 + t] = mfin[t];
    stats[((size_t)n * LCH + ck) * 8 + 4 + t] = lfin[t];
  }
  __syncthreads();

  // raw rowSumP[i][q][v] = sum_j w[i*64+j][q] * ct[j][v]  (16 local i-rows)
  for (int o = t; o < 512; o += 256) {
    int i = o >> 5, q = (o >> 3) & 3, v = o & 7;
    const float* wb = reinterpret_cast<const float*>(&wlds[i * 64]) + q;
    float s0 = 0.f, s1 = 0.f, s2 = 0.f, s3 = 0.f;
#pragma unroll 8
    for (int j = 0; j < 64; j += 4) {
      s0 += wb[(j + 0) * 4] * ct[j + 0][v];
      s1 += wb[(j + 1) * 4] * ct[j + 1][v];
      s2 += wb[(j + 2) * 4] * ct[j + 2][v];
      s3 += wb[(j + 3) * 4] * ct[j + 3][v];
    }
    rowSumP[(((size_t)n * LCH + ck) * 16 + i) * 32 + q * 8 + v] = (s0 + s1) + (s2 + s3);
  }

  if (ck == 0) {
    float* ap = ans + (size_t)n * 1026;
    for (int idx = t; idx < 288; idx += 256) ap[736 + idx] = Qs[idx / 72][idx % 72];
    if (t == 0) { ap[1024] = r_prev[n]; ap[1025] = a_prev[n]; }
  }
}

// ---------------------------------------------------------------- softmax merge + S-part
// 128 blocks x 256. Per n: global M,L per q; scales[n][ck][q] = exp(m_ck-M)/L;
// a_S[q][uv] = sum_ck scale * sum_i ct[ck*16+i][u] * rowSumP[ck][i][q][v].
__global__ __launch_bounds__(256) void k_fin(
    const float* __restrict__ stats, const float* __restrict__ rowSumP,
    float* __restrict__ scales, float* __restrict__ ans) {
  const int n = blockIdx.x, t = threadIdx.x;
  __shared__ float ct[64][8];
  __shared__ float sc[LCH][4];
  const float PI64 = 3.14159265358979323846f / 64.f;

  for (int e = t; e < 512; e += 256) {
    int i = e >> 3, u = e & 7;
    ct[i][u] = cosf((float)((i + 1) * (u + 1)) * PI64);
  }
  if (t < 16) {
    const int q = t & 3, ck = t >> 2;
    float M = -1e30f;
#pragma unroll
    for (int c = 0; c < LCH; ++c) M = fmaxf(M, stats[((size_t)n * LCH + c) * 8 + q]);
    float L = 0.f;
#pragma unroll
    for (int c = 0; c < LCH; ++c)
      L += stats[((size_t)n * LCH + c) * 8 + 4 + q] *
           __expf(stats[((size_t)n * LCH + c) * 8 + q] - M);
    sc[ck][q] = __expf(stats[((size_t)n * LCH + ck) * 8 + q] - M) / L;
  }
  __syncthreads();
  if (t < 16) scales[(size_t)n * 16 + t] = sc[t >> 2][t & 3];

  {
    const int q = t >> 6, uv = t & 63, u = uv >> 3, v = uv & 7;
    float s = 0.f;
#pragma unroll
    for (int ck = 0; ck < LCH; ++ck) {
      float ss = 0.f;
#pragma unroll 4
      for (int i = 0; i < 16; ++i)
        ss += ct[ck * 16 + i][u] *
              rowSumP[(((size_t)n * LCH + ck) * 16 + i) * 32 + q * 8 + v];
      s += sc[ck][q] * ss;
    }
    ans[(size_t)n * 1026 + q * 184 + 120 + uv] = s;
  }
}

// ---------------------------------------------------------------- weighted V (x-channels only)
// grid (PVCH, NTOT); block: 512 positions; wave: 128 positions;
// lane<60 owns x channels 8+2l, 8+2l+1; 16 loads in flight per lane.
__global__ __launch_bounds__(256, 4) void k_pv(
    const float* __restrict__ x, const float* __restrict__ Pw,
    float* __restrict__ pvp) {
  const int n = blockIdx.y, ck = blockIdx.x;
  const int t = threadIdx.x, wave = t >> 6, lane = t & 63;
  __shared__ float4 wl[PVLEN];
  __shared__ __align__(16) float part[4][4][120];

  const int base = ck * PVLEN;
  {
    const float4* src = reinterpret_cast<const float4*>(Pw) + (size_t)n * NPOS + base;
    wl[t] = src[t];
    wl[t + 256] = src[t + 256];
  }
  __syncthreads();

  const int xl = (lane < 60) ? lane : 59;
  const float* vb = x + ((size_t)n * NPOS + base + wave * 128) * 128 + 8 + 2 * xl;

  float ax0[4] = {0.f, 0.f, 0.f, 0.f};
  float ax1[4] = {0.f, 0.f, 0.f, 0.f};
#pragma unroll
  for (int b = 0; b < 8; ++b) {
    float2 v0  = *reinterpret_cast<const float2*>(vb + (size_t)(b * 16 + 0)  * 128);
    float2 v1  = *reinterpret_cast<const float2*>(vb + (size_t)(b * 16 + 1)  * 128);
    float2 v2  = *reinterpret_cast<const float2*>(vb + (size_t)(b * 16 + 2)  * 128);
    float2 v3  = *reinterpret_cast<const float2*>(vb + (size_t)(b * 16 + 3)  * 128);
    float2 v4  = *reinterpret_cast<const float2*>(vb + (size_t)(b * 16 + 4)  * 128);
    float2 v5  = *reinterpret_cast<const float2*>(vb + (size_t)(b * 16 + 5)  * 128);
    float2 v6  = *reinterpret_cast<const float2*>(vb + (size_t)(b * 16 + 6)  * 128);
    float2 v7  = *reinterpret_cast<const float2*>(vb + (size_t)(b * 16 + 7)  * 128);
    float2 v8  = *reinterpret_cast<const float2*>(vb + (size_t)(b * 16 + 8)  * 128);
    float2 v9  = *reinterpret_cast<const float2*>(vb + (size_t)(b * 16 + 9)  * 128);
    float2 v10 = *reinterpret_cast<const float2*>(vb + (size_t)(b * 16 + 10) * 128);
    float2 v11 = *reinterpret_cast<const float2*>(vb + (size_t)(b * 16 + 11) * 128);
    float2 v12 = *reinterpret_cast<const float2*>(vb + (size_t)(b * 16 + 12) * 128);
    float2 v13 = *reinterpret_cast<const float2*>(vb + (size_t)(b * 16 + 13) * 128);
    float2 v14 = *reinterpret_cast<const float2*>(vb + (size_t)(b * 16 + 14) * 128);
    float2 v15 = *reinterpret_cast<const float2*>(vb + (size_t)(b * 16 + 15) * 128);
#define ACC(VV, II)                                                              \
    {                                                                            \
      float4 w = wl[wave * 128 + b * 16 + II];                                   \
      ax0[0] += w.x * VV.x; ax1[0] += w.x * VV.y;                                \
      ax0[1] += w.y * VV.x; ax1[1] += w.y * VV.y;                                \
      ax0[2] += w.z * VV.x; ax1[2] += w.z * VV.y;                                \
      ax0[3] += w.w * VV.x; ax1[3] += w.w * VV.y;                                \
    }
    ACC(v0, 0)  ACC(v1, 1)  ACC(v2, 2)  ACC(v3, 3)
    ACC(v4, 4)  ACC(v5, 5)  ACC(v6, 6)  ACC(v7, 7)
    ACC(v8, 8)  ACC(v9, 9)  ACC(v10, 10) ACC(v11, 11)
    ACC(v12, 12) ACC(v13, 13) ACC(v14, 14) ACC(v15, 15)
#undef ACC
  }
  if (lane < 60) {
#pragma unroll
    for (int q = 0; q < 4; ++q)
      *reinterpret_cast<float2*>(&part[wave][q][2 * lane]) = make_float2(ax0[q], ax1[q]);
  }
  __syncthreads();

  float* op = pvp + ((size_t)ck * NTOT + n) * 480;
  for (int idx = t; idx < 480; idx += 256) {
    const int q = idx / 120, d = idx - q * 120;
    op[idx] = (part[0][q][d] + part[1][q][d]) + (part[2][q][d] + part[3][q][d]);
  }
}

// ---------------------------------------------------------------- LSTM gates (fused a-mlp out reduce, z=8)
__global__ __launch_bounds__(256) void k_gates(
    const float* __restrict__ pA, const float* __restrict__ biasA,
    const float* __restrict__ hp,
    const float* __restrict__ w_ih, const float* __restrict__ w_hh,
    const float* __restrict__ b_ih, const float* __restrict__ b_hh,
    float* __restrict__ gbuf) {
  const int t = threadIdx.x;
  const int n0 = blockIdx.x * 2;
  const int r0 = blockIdx.y * 64;
  __shared__ float xs[2][256], hs[2][256];
  __shared__ float red[64][4][5];
#pragma unroll
  for (int s = 0; s < 2; ++s) {
    float v0 = biasA[t], v1 = 0.f, v2 = 0.f, v3 = 0.f;
#pragma unroll
    for (int z = 0; z < 8; z += 4) {
      v0 += pA[((size_t)(z + 0) * NTOT + n0 + s) * 256 + t];
      v1 += pA[((size_t)(z + 1) * NTOT + n0 + s) * 256 + t];
      v2 += pA[((size_t)(z + 2) * NTOT + n0 + s) * 256 + t];
      v3 += pA[((size_t)(z + 3) * NTOT + n0 + s) * 256 + t];
    }
    xs[s][t] = (v0 + v1) + (v2 + v3);
    hs[s][t] = hp[(size_t)(n0 + s) * 256 + t];
  }
  __syncthreads();
  const int r = t >> 2, kq = t & 3;
  const int row = r0 + r;
  const float4* wi = reinterpret_cast<const float4*>(w_ih + (size_t)row * 256 + kq * 64);
  const float4* wh = reinterpret_cast<const float4*>(w_hh + (size_t)row * 256 + kq * 64);
  float s00 = 0.f, s01 = 0.f, s10 = 0.f, s11 = 0.f;
#pragma unroll
  for (int i = 0; i < 16; ++i) {
    float4 a = wi[i], b = wh[i];
    const int k4 = kq * 64 + i * 4;
    s00 += a.x * xs[0][k4] + a.y * xs[0][k4 + 1] + a.z * xs[0][k4 + 2] + a.w * xs[0][k4 + 3];
    s01 += a.x * xs[1][k4] + a.y * xs[1][k4 + 1] + a.z * xs[1][k4 + 2] + a.w * xs[1][k4 + 3];
    s10 += b.x * hs[0][k4] + b.y * hs[0][k4 + 1] + b.z * hs[0][k4 + 2] + b.w * hs[0][k4 + 3];
    s11 += b.x * hs[1][k4] + b.y * hs[1][k4 + 1] + b.z * hs[1][k4 + 2] + b.w * hs[1][k4 + 3];
  }
  red[r][kq][0] = s00; red[r][kq][1] = s01; red[r][kq][2] = s10; red[r][kq][3] = s11;
  __syncthreads();
  if (t < 128) {
    const int rr = t >> 1, s = t & 1;
    float g = b_ih[r0 + rr] + b_hh[r0 + rr];
#pragma unroll
    for (int k = 0; k < 4; ++k) g += red[rr][k][s] + red[rr][k][2 + s];
    gbuf[(size_t)(n0 + s) * 1024 + r0 + rr] = g;
  }
}

// ---------------------------------------------------------------- LSTM elementwise + heads
__global__ __launch_bounds__(256) void k_lstm2(
    const float* __restrict__ gbuf, const float* __restrict__ cp,
    const float* __restrict__ p_w, const float* __restrict__ p_b,
    const float* __restrict__ v_w, const float* __restrict__ v_b,
    float* __restrict__ out) {
  const int t = threadIdx.x;
  const int n0 = blockIdx.x * 2;
  __shared__ float h2[2][256];
#pragma unroll
  for (int s = 0; s < 2; ++s) {
    const size_t gb = (size_t)(n0 + s) * 1024;
    float gi = gbuf[gb + t], gf = gbuf[gb + 256 + t];
    float gg = gbuf[gb + 512 + t], go = gbuf[gb + 768 + t];
    float si = 1.f / (1.f + __expf(-gi));
    float sf = 1.f / (1.f + __expf(-gf));
    float so = 1.f / (1.f + __expf(-go));
    float c2 = sf * cp[(size_t)(n0 + s) * 256 + t] + si * tanhf(gg);
    h2[s][t] = so * tanhf(c2);
  }
  __syncthreads();
  if (t < 72) {
    const int si = t / 36, r = t % 36, iv = r / 18, j = r % 18;
    const float* W = iv ? v_w : p_w;
    const float* B = iv ? v_b : p_b;
    float s = B[j];
#pragma unroll 8
    for (int k = 0; k < 256; ++k) s += h2[si][k] * W[k * 18 + j];
    out[(size_t)iv * (NTOT * 18) + (size_t)(n0 + si) * 18 + j] = s;
  }
}

// ---------------------------------------------------------------- launch
extern "C" void kernel_launch(void* const* d_in, const int* in_sizes, int n_in,
                              void* d_out, int out_size, void* d_ws, size_t ws_size,
                              hipStream_t stream) {
  const float* x      = (const float*)d_in[0];
  const int*   cptr   = (const int*)d_in[1];
  const float* r_prev = (const float*)d_in[2];
  const float* a_prev = (const float*)d_in[3];
  const float* hprev  = (const float*)d_in[4];
  const float* cprev  = (const float*)d_in[5];
  const float* q_w0 = (const float*)d_in[6];
  const float* q_b0 = (const float*)d_in[7];
  const float* q_w1 = (const float*)d_in[8];
  const float* q_b1 = (const float*)d_in[9];
  const float* q_w2 = (const float*)d_in[10];
  const float* q_b2 = (const float*)d_in[11];
  const float* a_w0 = (const float*)d_in[12];
  const float* a_b0 = (const float*)d_in[13];
  const float* a_w1 = (const float*)d_in[14];
  const float* a_b1 = (const float*)d_in[15];
  const float* a_w2 = (const float*)d_in[16];
  const float* a_b2 = (const float*)d_in[17];
  const float* w_ih = (const float*)d_in[18];
  const float* w_hh = (const float*)d_in[19];
  const float* b_ih = (const float*)d_in[20];
  const float* b_hh = (const float*)d_in[21];
  const float* p_w  = (const float*)d_in[22];
  const float* p_b  = (const float*)d_in[23];
  const float* v_w  = (const float*)d_in[24];
  const float* v_b  = (const float*)d_in[25];
  float* out = (float*)d_out;
  float* ws  = (float*)d_ws;

  // workspace layout (floats)
  float* pQ   = ws;                 // 294912  (8 x 128 x 288) q_w2 partials
  float* pb1  = pQ   + 294912;      // 589824  (9 x 128 x 512)
  float* pb2  = pb1  + 589824;      // 524288  (8 x 128 x 512)
  float* pb3  = pb2  + 524288;      // 262144  (8 x 128 x 256)
  float* Pw   = pb3  + 262144;      // 2097152 (128 x 4096 x 4) unnormalized weights
  float* pvp  = Pw   + 2097152;     // 491520  (8 x 128 x 480) pv partials
  float* ans  = pvp  + 491520;      // 131328  (128 x 1026)
  float* gbuf = ans  + 131328;      // 131072  (128 x 1024)
  float* stats= gbuf + 131072;      // 4096    (128 x 4 x 8) chunk m,l
  float* rsum = stats+ 4096;        // 262144  (128 x 4 x 16 x 32) raw rowSums
  float* scl  = rsum + 262144;      // 2048    (128 x 4 x 4) softmax scales

  // q-mlp: hprev(128,256) -> 512 -> 512 -> Q partials (288 cols at offset c*288)
  k_gemm<<<dim3(2, 32, 4), 256, 0, stream>>>(hprev, nullptr, nullptr, 0, 0, nullptr, nullptr,
                                             q_w0, pb1, 512, 256, 512, 64, cptr, 0);
  k_gemm<<<dim3(2, 32, 8), 256, 0, stream>>>(nullptr, pb1, q_b0, 4, 1, nullptr, nullptr,
                                             q_w1, pb2, 512, 512, 512, 64, cptr, 0);
  k_gemm<<<dim3(2, 32, 8), 256, 0, stream>>>(nullptr, pb2, q_b1, 8, 1, nullptr, nullptr,
                                             q_w2, pQ, 288, 512, 1152, 64, cptr, 288);

  // attention: chunked logits/softmax -> pv partials -> merge (scales + S-part)
  k_logit_part<<<dim3(LCH, NTOT), 256, 0, stream>>>(x, pQ, q_b2, cptr, r_prev, a_prev,
                                                    Pw, stats, rsum, ans);
  k_pv<<<dim3(PVCH, NTOT), 256, 0, stream>>>(x, Pw, pvp);
  k_fin<<<NTOT, 256, 0, stream>>>(stats, rsum, scl, ans);

  // a-mlp: ans(128,1026) -> 512 -> 512 -> 256; first layer gather-reduces pvp w/ scales
  k_gemm<<<dim3(2, 32, 9), 256, 0, stream>>>(ans, nullptr, nullptr, 0, 0, pvp, scl,
                                             a_w0, pb1, 512, 1026, 512, 128, cptr, 0);
  k_gemm<<<dim3(2, 32, 8), 256, 0, stream>>>(nullptr, pb1, a_b0, 9, 1, nullptr, nullptr,
                                             a_w1, pb2, 512, 512, 512, 64, cptr, 0);
  k_gemm<<<dim3(1, 32, 8), 256, 0, stream>>>(nullptr, pb2, a_b1, 8, 1, nullptr, nullptr,
                                             a_w2, pb3, 256, 512, 256, 64, cptr, 0);

  // LSTM + heads (am reduced in-block from pb3, z=8)
  k_gates<<<dim3(64, 16), 256, 0, stream>>>(pb3, a_b2, hprev, w_ih, w_hh, b_ih, b_hh, gbuf);
  k_lstm2<<<64, 256, 0, stream>>>(gbuf, cprev, p_w, p_b, v_w, v_b, out);
}